// Round 14
// baseline (111.901 us; speedup 1.0000x reference)
//
#include <hip/hip_runtime.h>
#include <math.h>

#define DHID 128
#define NCLS 40
#define ELLW 64

typedef unsigned int   u32;
typedef unsigned short u16;
using short8 = __attribute__((ext_vector_type(8))) short;
using f32x4  = __attribute__((ext_vector_type(4))) float;

// round-to-nearest-even f32 -> bf16
__device__ __forceinline__ u16 f2bf(float f) {
  u32 u = __float_as_uint(f);
  return (u16)((u + 0x7FFFu + ((u >> 16) & 1u)) >> 16);
}
__device__ __forceinline__ float bf_lo(u32 p) { return __uint_as_float(p << 16); }
__device__ __forceinline__ float bf_hi(u32 p) { return __uint_as_float(p & 0xFFFF0000u); }

__device__ __forceinline__ short8 packbf(float4 a, float4 b) {
  short8 r;
  r[0] = (short)f2bf(a.x); r[1] = (short)f2bf(a.y);
  r[2] = (short)f2bf(a.z); r[3] = (short)f2bf(a.w);
  r[4] = (short)f2bf(b.x); r[5] = (short)f2bf(b.y);
  r[6] = (short)f2bf(b.z); r[7] = (short)f2bf(b.w);
  return r;
}

// ============ K0: prep = zero(counts,ssum,ovf) + pack W1/W2 frags ===========
__global__ __launch_bounds__(256) void prep_kernel(
    const float* __restrict__ W1, const float* __restrict__ W2,
    u16* __restrict__ Wp1, u16* __restrict__ Wp2,
    int* __restrict__ counts, float* __restrict__ ssum,
    int* __restrict__ ovf_cnt, int N) {
  int gi = blockIdx.x * 256 + threadIdx.x;
  if (gi < N) { counts[gi] = 0; ssum[gi] = 0.f; return; }
  gi -= N;
  if (gi < 32768) {                        // 2 layers x 16384
    int layer = gi >> 14, q = gi & 16383;
    int j = q & 7, l = (q >> 3) & 63, kt = (q >> 9) & 3, ct = q >> 11;
    int k = kt * 32 + (l >> 4) * 8 + j;
    int col = ct * 16 + (l & 15);
    const float* Wsrc = layer ? W2 : W1;
    u16* Wdst = layer ? Wp2 : Wp1;
    Wdst[q] = f2bf(Wsrc[k * DHID + col]);
    return;
  }
  gi -= 32768;
  if (gi == 0) *ovf_cnt = 0;
}

// ============ MFMA GEMM block: H[rowBase..+32] = bf16(X @ W), el, er ========
template <bool BF16IN>
__device__ __forceinline__ void mfma_gemm_block(
    float* Cl, float* P, const float* __restrict__ Xf,
    const u16* __restrict__ Xh, const u16* __restrict__ Wp,
    const float* __restrict__ aW, u16* __restrict__ Hout,
    float* __restrict__ elo, float* __restrict__ ero, int n, int rowBase) {
  int t = threadIdx.x;
  int w = t >> 6, l = t & 63;
  int lr = l & 15, lh = l >> 4;
  f32x4 acc00 = {0.f,0.f,0.f,0.f}, acc01 = {0.f,0.f,0.f,0.f};
  f32x4 acc10 = {0.f,0.f,0.f,0.f}, acc11 = {0.f,0.f,0.f,0.f};
  int r0 = rowBase + lr;      if (r0 > n - 1) r0 = n - 1;
  int r1 = rowBase + 16 + lr; if (r1 > n - 1) r1 = n - 1;
  const u16* wb0 = Wp + ((size_t)(w * 2 + 0) * 4 * 64 + l) * 8;
  const u16* wb1 = Wp + ((size_t)(w * 2 + 1) * 4 * 64 + l) * 8;
#pragma unroll
  for (int kt = 0; kt < 4; ++kt) {
    int ko = kt * 32 + lh * 8;
    short8 fa0, fa1;
    if constexpr (BF16IN) {
      fa0 = *reinterpret_cast<const short8*>(Xh + (size_t)r0 * DHID + ko);
      fa1 = *reinterpret_cast<const short8*>(Xh + (size_t)r1 * DHID + ko);
    } else {
      const float* a0f = Xf + (size_t)r0 * DHID + ko;
      const float* a1f = Xf + (size_t)r1 * DHID + ko;
      fa0 = packbf(*reinterpret_cast<const float4*>(a0f),
                   *reinterpret_cast<const float4*>(a0f + 4));
      fa1 = packbf(*reinterpret_cast<const float4*>(a1f),
                   *reinterpret_cast<const float4*>(a1f + 4));
    }
    short8 fb0 = *reinterpret_cast<const short8*>(wb0 + kt * 64 * 8);
    short8 fb1 = *reinterpret_cast<const short8*>(wb1 + kt * 64 * 8);
    acc00 = __builtin_amdgcn_mfma_f32_16x16x32_bf16(fa0, fb0, acc00, 0, 0, 0);
    acc01 = __builtin_amdgcn_mfma_f32_16x16x32_bf16(fa0, fb1, acc01, 0, 0, 0);
    acc10 = __builtin_amdgcn_mfma_f32_16x16x32_bf16(fa1, fb0, acc10, 0, 0, 0);
    acc11 = __builtin_amdgcn_mfma_f32_16x16x32_bf16(fa1, fb1, acc11, 0, 0, 0);
  }
#pragma unroll
  for (int j = 0; j < 4; ++j) {
    Cl[(lh * 4 + j) * DHID + w * 32 + lr]           = acc00[j];
    Cl[(lh * 4 + j) * DHID + w * 32 + 16 + lr]      = acc01[j];
    Cl[(16 + lh * 4 + j) * DHID + w * 32 + lr]      = acc10[j];
    Cl[(16 + lh * 4 + j) * DHID + w * 32 + 16 + lr] = acc11[j];
  }
  __syncthreads();
  int r = t >> 3, cg2 = (t & 7) * 16;
  const float* crow = Cl + r * DHID + cg2;
  float pl = 0.f, pr = 0.f;
  int gr = rowBase + r;
#pragma unroll
  for (int q = 0; q < 16; ++q) {
    float v = crow[q];
    pl = fmaf(v, aW[cg2 + q], pl);
    pr = fmaf(v, aW[DHID + cg2 + q], pr);
  }
  if (gr < n) {
    uint4 o;
    o.x = (u32)f2bf(crow[0])  | ((u32)f2bf(crow[1])  << 16);
    o.y = (u32)f2bf(crow[2])  | ((u32)f2bf(crow[3])  << 16);
    o.z = (u32)f2bf(crow[4])  | ((u32)f2bf(crow[5])  << 16);
    o.w = (u32)f2bf(crow[6])  | ((u32)f2bf(crow[7])  << 16);
    *reinterpret_cast<uint4*>(Hout + (size_t)gr * DHID + cg2) = o;
    uint4 o2;
    o2.x = (u32)f2bf(crow[8])  | ((u32)f2bf(crow[9])  << 16);
    o2.y = (u32)f2bf(crow[10]) | ((u32)f2bf(crow[11]) << 16);
    o2.z = (u32)f2bf(crow[12]) | ((u32)f2bf(crow[13]) << 16);
    o2.w = (u32)f2bf(crow[14]) | ((u32)f2bf(crow[15]) << 16);
    *reinterpret_cast<uint4*>(Hout + (size_t)gr * DHID + cg2 + 8) = o2;
  }
  P[r * 16 + (t & 7) * 2 + 0] = pl;
  P[r * 16 + (t & 7) * 2 + 1] = pr;
  __syncthreads();
  if (t < 64) {
    int half = t >> 5, rr = t & 31;
    float s = 0.f;
#pragma unroll
    for (int cq = 0; cq < 8; ++cq) s += P[rr * 16 + cq * 2 + half];
    int g2 = rowBase + rr;
    if (g2 < n) { if (half) ero[g2] = s; else elo[g2] = s; }
  }
}

// ============ K2: mfma gemm1 (fp32 in, blocks < gT) || ELL build ============
__global__ __launch_bounds__(256) void gemm1_build_kernel(
    const float* __restrict__ X, const u16* __restrict__ Wp,
    const float* __restrict__ aW, u16* __restrict__ H,
    float* __restrict__ el, float* __restrict__ er, int n, int gT,
    const int* __restrict__ ei, const float* __restrict__ norm,
    int* __restrict__ counts, float* __restrict__ ssum,
    uint2* __restrict__ ell, uint4* __restrict__ ovf,
    int* __restrict__ ovf_cnt, int E, int EP) {
  __shared__ float Cl[32 * DHID];   // 16 KB
  __shared__ float P[32 * 16];      // 2 KB
  if (blockIdx.x < gT) {
    mfma_gemm_block<false>(Cl, P, X, nullptr, Wp, aW, H, el, er, n,
                           blockIdx.x * 32);
  } else {
    int k = (blockIdx.x - gT) * 256 + threadIdx.x;
    if (k < EP) {
      int src, dst;
      if (k < E) { src = ei[k]; dst = ei[E + k]; }
      else       { src = dst = k - E; }
      float se = __expf(norm[k]);
      atomicAdd(&ssum[src], se);
      int slot = atomicAdd(&counts[dst], 1);
      if (slot < ELLW) {
        ell[(size_t)dst * ELLW + slot] =
            make_uint2((u32)src, __float_as_uint(se));
      } else {
        int o = atomicAdd(ovf_cnt, 1);
        ovf[o] = make_uint4((u32)dst, (u32)src, __float_as_uint(se), 0u);
      }
    }
  }
}

// ============ K4: standalone mfma gemm2 (bf16 in) ===========================
__global__ __launch_bounds__(256) void gemm_elr_kernel(
    const u16* __restrict__ Xbf, const u16* __restrict__ Wp,
    const float* __restrict__ aW, u16* __restrict__ H,
    float* __restrict__ el, float* __restrict__ er, int n) {
  __shared__ float Cl[32 * DHID];
  __shared__ float P[32 * 16];
  mfma_gemm_block<true>(Cl, P, nullptr, Xbf, Wp, aW, H, el, er, n,
                        blockIdx.x * 32);
}

// ============ K3: agg1, feature-split + XCD-affine halves ===================
// Block b: pair=b>>3, r=b&7 (XCD via blockIdx%8 round-robin), h=r>>2 is the
// feature half (XCDs 0-3 gather only features 0..63, XCDs 4-7 features
// 64..127 -> per-XCD H footprint 2.56MB, fits the 4MB L2). Wave = one
// (node, half): 8 lanes x uint4 covers 64 features; 8 edges per wave-load.
__global__ __launch_bounds__(256) void agg1_split_kernel(
    const u16* __restrict__ H, const int* __restrict__ counts,
    const uint2* __restrict__ ell, const uint4* __restrict__ ovf,
    const int* __restrict__ ovf_cnt, const float* __restrict__ el,
    const float* __restrict__ er, const float* __restrict__ ssum,
    const float* __restrict__ ab, const float* __restrict__ alpha,
    const float* __restrict__ bias, u16* __restrict__ Y, int n, int ngrp) {
  int b = blockIdx.x;
  int pair = b >> 3, r = b & 7;
  int h = r >> 2;                       // feature half for this XCD group
  int g = pair * 4 + (r & 3);           // node group (4 nodes)
  if (g >= ngrp) return;
  int wv = threadIdx.x >> 6, lane = threadIdx.x & 63;
  int node = g * 4 + wv;
  if (node >= n) return;

  int ovfN = *ovf_cnt;
  float al = fminf(fmaxf(alpha[0], 1e-4f), 0.9999f);
  float base = er[node] + ab[0];

  int deg = counts[node];
  int dell = deg < ELLW ? deg : ELLW;
  const uint2* erow = ell + (size_t)node * ELLW;
  int src0 = 0; float sx0 = 0.f;
  if (lane < dell) {
    uint2 rec = erow[lane];
    src0 = (int)rec.x;
    sx0  = __uint_as_float(rec.y);
  }
  // prefetch edges 0..15 (2 wave-loads), overlapped with softmax below
  int eo = lane >> 3;                   // edge offset within flight group
  const u16* Hf = H + h * 64 + ((lane & 7) << 3);
  int c0 = eo < dell ? eo : 0;
  int e1 = 8 + eo;
  int c1 = e1 < dell ? e1 : 0;
  int ps0 = __shfl(src0, c0);
  int ps1 = __shfl(src0, c1);
  uint4 pr0 = *reinterpret_cast<const uint4*>(Hf + (size_t)ps0 * DHID);
  uint4 pr1 = *reinterpret_cast<const uint4*>(Hf + (size_t)ps1 * DHID);
  // softmax denominator
  float e0 = 0.f;
  if (lane < dell) {
    float gl = el[src0] + base;
    e0 = __expf(gl > 0.f ? gl : 0.2f * gl);
  }
  float es = e0;
  if (ovfN > 0 && deg > ELLW) {
    for (int cb = 0; cb < ovfN; cb += 64) {
      int i = cb + lane;
      if (i < ovfN) {
        uint4 rr2 = ovf[i];
        if ((int)rr2.x == node) {
          float gl = el[(int)rr2.y] + base;
          es += __expf(gl > 0.f ? gl : 0.2f * gl);
        }
      }
    }
  }
#pragma unroll
  for (int off = 32; off; off >>= 1) es += __shfl_xor(es, off);
  float invEs = al / es;
  float omaS  = (1.f - al) / ssum[node];
  float w0 = e0 * invEs + sx0 * omaS;

  float a[8];
#pragma unroll
  for (int i = 0; i < 8; ++i) a[i] = -INFINITY;
  // consume prefetched
  {
    float wA = __shfl(w0, c0);
    float wB = __shfl(w0, c1);
    if (eo < dell) {
      a[0] = fmaxf(a[0], wA * bf_lo(pr0.x)); a[1] = fmaxf(a[1], wA * bf_hi(pr0.x));
      a[2] = fmaxf(a[2], wA * bf_lo(pr0.y)); a[3] = fmaxf(a[3], wA * bf_hi(pr0.y));
      a[4] = fmaxf(a[4], wA * bf_lo(pr0.z)); a[5] = fmaxf(a[5], wA * bf_hi(pr0.z));
      a[6] = fmaxf(a[6], wA * bf_lo(pr0.w)); a[7] = fmaxf(a[7], wA * bf_hi(pr0.w));
    }
    if (e1 < dell) {
      a[0] = fmaxf(a[0], wB * bf_lo(pr1.x)); a[1] = fmaxf(a[1], wB * bf_hi(pr1.x));
      a[2] = fmaxf(a[2], wB * bf_lo(pr1.y)); a[3] = fmaxf(a[3], wB * bf_hi(pr1.y));
      a[4] = fmaxf(a[4], wB * bf_lo(pr1.z)); a[5] = fmaxf(a[5], wB * bf_hi(pr1.z));
      a[6] = fmaxf(a[6], wB * bf_lo(pr1.w)); a[7] = fmaxf(a[7], wB * bf_hi(pr1.w));
    }
  }
  // stream remaining edges, 8 per wave-load
  int j = 16;
  for (; j + 7 < dell; j += 8) {
    int e = j + eo;
    int   sa = __shfl(src0, e); float wa = __shfl(w0, e);
    uint4 ha = *reinterpret_cast<const uint4*>(Hf + (size_t)sa * DHID);
    a[0] = fmaxf(a[0], wa * bf_lo(ha.x)); a[1] = fmaxf(a[1], wa * bf_hi(ha.x));
    a[2] = fmaxf(a[2], wa * bf_lo(ha.y)); a[3] = fmaxf(a[3], wa * bf_hi(ha.y));
    a[4] = fmaxf(a[4], wa * bf_lo(ha.z)); a[5] = fmaxf(a[5], wa * bf_hi(ha.z));
    a[6] = fmaxf(a[6], wa * bf_lo(ha.w)); a[7] = fmaxf(a[7], wa * bf_hi(ha.w));
  }
  if (j < dell) {                       // tail, <=7 edges
    int e = j + eo;
    int ec = e < dell ? e : dell - 1;
    int   sa = __shfl(src0, ec); float wa = __shfl(w0, ec);
    if (e < dell) {
      uint4 ha = *reinterpret_cast<const uint4*>(Hf + (size_t)sa * DHID);
      a[0] = fmaxf(a[0], wa * bf_lo(ha.x)); a[1] = fmaxf(a[1], wa * bf_hi(ha.x));
      a[2] = fmaxf(a[2], wa * bf_lo(ha.y)); a[3] = fmaxf(a[3], wa * bf_hi(ha.y));
      a[4] = fmaxf(a[4], wa * bf_lo(ha.z)); a[5] = fmaxf(a[5], wa * bf_hi(ha.z));
      a[6] = fmaxf(a[6], wa * bf_lo(ha.w)); a[7] = fmaxf(a[7], wa * bf_hi(ha.w));
    }
  }
  // overflow gather (rare)
  if (ovfN > 0 && deg > ELLW) {
    for (int cb = 0; cb < ovfN; cb += 64) {
      int i = cb + lane;
      uint4 rr2 = (i < ovfN) ? ovf[i] : make_uint4(0u, 0u, 0u, 0u);
      bool match = (i < ovfN) && ((int)rr2.x == node);
      int si = (int)rr2.y;
      float wi = 0.f;
      if (match) {
        float gl = el[si] + base;
        wi = __expf(gl > 0.f ? gl : 0.2f * gl) * invEs +
             __uint_as_float(rr2.z) * omaS;
      }
      unsigned long long mask = __ballot(match);
      while (mask) {
        int jb = __ffsll(mask) - 1;
        mask &= mask - 1;
        int   sj = __shfl(si, jb);
        float wj = __shfl(wi, jb);
        uint4 hq = *reinterpret_cast<const uint4*>(Hf + (size_t)sj * DHID);
        a[0] = fmaxf(a[0], wj * bf_lo(hq.x)); a[1] = fmaxf(a[1], wj * bf_hi(hq.x));
        a[2] = fmaxf(a[2], wj * bf_lo(hq.y)); a[3] = fmaxf(a[3], wj * bf_hi(hq.y));
        a[4] = fmaxf(a[4], wj * bf_lo(hq.z)); a[5] = fmaxf(a[5], wj * bf_hi(hq.z));
        a[6] = fmaxf(a[6], wj * bf_lo(hq.w)); a[7] = fmaxf(a[7], wj * bf_hi(hq.w));
      }
    }
  }
  // reduce across the 8 edge-groups (lane bits 3,4,5)
#pragma unroll
  for (int i = 0; i < 8; ++i) {
    a[i] = fmaxf(a[i], __shfl_xor(a[i], 8));
    a[i] = fmaxf(a[i], __shfl_xor(a[i], 16));
    a[i] = fmaxf(a[i], __shfl_xor(a[i], 32));
  }
  if (lane < 8) {
    int fl = h * 64 + (lane << 3);
    float v[8];
#pragma unroll
    for (int i = 0; i < 8; ++i) v[i] = fmaxf(a[i] + bias[fl + i], 0.f);
    uint4 o;
    o.x = (u32)f2bf(v[0]) | ((u32)f2bf(v[1]) << 16);
    o.y = (u32)f2bf(v[2]) | ((u32)f2bf(v[3]) << 16);
    o.z = (u32)f2bf(v[4]) | ((u32)f2bf(v[5]) << 16);
    o.w = (u32)f2bf(v[6]) | ((u32)f2bf(v[7]) << 16);
    *reinterpret_cast<uint4*>(Y + (size_t)node * DHID + fl) = o;
  }
}

// ============ full-feature agg (used by K5) =================================
__device__ __forceinline__ void agg_node8(
    const u16* __restrict__ H, const int* __restrict__ counts,
    const uint2* __restrict__ ell, const uint4* __restrict__ ovf, int ovfN,
    const float* __restrict__ el, const float* __restrict__ ssum,
    float base, float al, int node, int lane, float a[8]) {
  int deg = counts[node];
  int dell = deg < ELLW ? deg : ELLW;
  const uint2* erow = ell + (size_t)node * ELLW;
  int src0 = 0; float sx0 = 0.f;
  if (lane < dell) {
    uint2 rec = erow[lane];
    src0 = (int)rec.x;
    sx0  = __uint_as_float(rec.y);
  }
  int qw = lane >> 4;
  const u16* Hf = H + ((lane & 15) << 3);
  int ei0 = qw, ei1 = 4 + qw;
  int ci0 = ei0 < dell ? ei0 : 0;
  int ci1 = ei1 < dell ? ei1 : 0;
  int ps0 = __shfl(src0, ci0);
  int ps1 = __shfl(src0, ci1);
  uint4 pr0 = *reinterpret_cast<const uint4*>(Hf + (size_t)ps0 * DHID);
  uint4 pr1 = *reinterpret_cast<const uint4*>(Hf + (size_t)ps1 * DHID);
  float e0 = 0.f;
  if (lane < dell) {
    float g = el[src0] + base;
    e0 = __expf(g > 0.f ? g : 0.2f * g);
  }
  float es = e0;
  if (ovfN > 0 && deg > ELLW) {
    for (int cb = 0; cb < ovfN; cb += 64) {
      int i = cb + lane;
      if (i < ovfN) {
        uint4 r = ovf[i];
        if ((int)r.x == node) {
          float g = el[(int)r.y] + base;
          es += __expf(g > 0.f ? g : 0.2f * g);
        }
      }
    }
  }
#pragma unroll
  for (int off = 32; off; off >>= 1) es += __shfl_xor(es, off);
  float invEs = al / es;
  float omaS  = (1.f - al) / ssum[node];
  float w0 = e0 * invEs + sx0 * omaS;
#pragma unroll
  for (int i = 0; i < 8; ++i) a[i] = -INFINITY;
  {
    float wA = __shfl(w0, ci0);
    float wB = __shfl(w0, ci1);
    if (ei0 < dell) {
      a[0] = fmaxf(a[0], wA * bf_lo(pr0.x)); a[1] = fmaxf(a[1], wA * bf_hi(pr0.x));
      a[2] = fmaxf(a[2], wA * bf_lo(pr0.y)); a[3] = fmaxf(a[3], wA * bf_hi(pr0.y));
      a[4] = fmaxf(a[4], wA * bf_lo(pr0.z)); a[5] = fmaxf(a[5], wA * bf_hi(pr0.z));
      a[6] = fmaxf(a[6], wA * bf_lo(pr0.w)); a[7] = fmaxf(a[7], wA * bf_hi(pr0.w));
    }
    if (ei1 < dell) {
      a[0] = fmaxf(a[0], wB * bf_lo(pr1.x)); a[1] = fmaxf(a[1], wB * bf_hi(pr1.x));
      a[2] = fmaxf(a[2], wB * bf_lo(pr1.y)); a[3] = fmaxf(a[3], wB * bf_hi(pr1.y));
      a[4] = fmaxf(a[4], wB * bf_lo(pr1.z)); a[5] = fmaxf(a[5], wB * bf_hi(pr1.z));
      a[6] = fmaxf(a[6], wB * bf_lo(pr1.w)); a[7] = fmaxf(a[7], wB * bf_hi(pr1.w));
    }
  }
  int j = 8;
  for (; j + 7 < dell; j += 8) {
    int ea = j + qw, eb = j + 4 + qw;
    int   sa = __shfl(src0, ea); float wa = __shfl(w0, ea);
    int   sb = __shfl(src0, eb); float wb = __shfl(w0, eb);
    uint4 ha = *reinterpret_cast<const uint4*>(Hf + (size_t)sa * DHID);
    uint4 hb = *reinterpret_cast<const uint4*>(Hf + (size_t)sb * DHID);
    a[0] = fmaxf(a[0], fmaxf(wa * bf_lo(ha.x), wb * bf_lo(hb.x)));
    a[1] = fmaxf(a[1], fmaxf(wa * bf_hi(ha.x), wb * bf_hi(hb.x)));
    a[2] = fmaxf(a[2], fmaxf(wa * bf_lo(ha.y), wb * bf_lo(hb.y)));
    a[3] = fmaxf(a[3], fmaxf(wa * bf_hi(ha.y), wb * bf_hi(hb.y)));
    a[4] = fmaxf(a[4], fmaxf(wa * bf_lo(ha.z), wb * bf_lo(hb.z)));
    a[5] = fmaxf(a[5], fmaxf(wa * bf_hi(ha.z), wb * bf_hi(hb.z)));
    a[6] = fmaxf(a[6], fmaxf(wa * bf_lo(ha.w), wb * bf_lo(hb.w)));
    a[7] = fmaxf(a[7], fmaxf(wa * bf_hi(ha.w), wb * bf_hi(hb.w)));
  }
  for (; j < dell; j += 4) {
    int e = j + qw;
    int ec = e < dell ? e : dell - 1;
    int   sa = __shfl(src0, ec); float wa = __shfl(w0, ec);
    if (e < dell) {
      uint4 ha = *reinterpret_cast<const uint4*>(Hf + (size_t)sa * DHID);
      a[0] = fmaxf(a[0], wa * bf_lo(ha.x));
      a[1] = fmaxf(a[1], wa * bf_hi(ha.x));
      a[2] = fmaxf(a[2], wa * bf_lo(ha.y));
      a[3] = fmaxf(a[3], wa * bf_hi(ha.y));
      a[4] = fmaxf(a[4], wa * bf_lo(ha.z));
      a[5] = fmaxf(a[5], wa * bf_hi(ha.z));
      a[6] = fmaxf(a[6], wa * bf_lo(ha.w));
      a[7] = fmaxf(a[7], wa * bf_hi(ha.w));
    }
  }
  if (ovfN > 0 && deg > ELLW) {
    for (int cb = 0; cb < ovfN; cb += 64) {
      int i = cb + lane;
      uint4 r = (i < ovfN) ? ovf[i] : make_uint4(0u, 0u, 0u, 0u);
      bool match = (i < ovfN) && ((int)r.x == node);
      int si = (int)r.y;
      float wi = 0.f;
      if (match) {
        float g = el[si] + base;
        wi = __expf(g > 0.f ? g : 0.2f * g) * invEs +
             __uint_as_float(r.z) * omaS;
      }
      unsigned long long mask = __ballot(match);
      while (mask) {
        int jb = __ffsll(mask) - 1;
        mask &= mask - 1;
        int   sj = __shfl(si, jb);
        float wj = __shfl(wi, jb);
        uint4 h = *reinterpret_cast<const uint4*>(Hf + (size_t)sj * DHID);
        a[0] = fmaxf(a[0], wj * bf_lo(h.x)); a[1] = fmaxf(a[1], wj * bf_hi(h.x));
        a[2] = fmaxf(a[2], wj * bf_lo(h.y)); a[3] = fmaxf(a[3], wj * bf_hi(h.y));
        a[4] = fmaxf(a[4], wj * bf_lo(h.z)); a[5] = fmaxf(a[5], wj * bf_hi(h.z));
        a[6] = fmaxf(a[6], wj * bf_lo(h.w)); a[7] = fmaxf(a[7], wj * bf_hi(h.w));
      }
    }
  }
#pragma unroll
  for (int i = 0; i < 8; ++i) {
    a[i] = fmaxf(a[i], __shfl_xor(a[i], 16));
    a[i] = fmaxf(a[i], __shfl_xor(a[i], 32));
  }
}

// ============ K5: agg2 + head ===============================================
__global__ __launch_bounds__(256) void agg_head_kernel(
    const u16* __restrict__ H, const int* __restrict__ counts,
    const uint2* __restrict__ ell, const uint4* __restrict__ ovf,
    const int* __restrict__ ovf_cnt, const float* __restrict__ el,
    const float* __restrict__ er, const float* __restrict__ ssum,
    const float* __restrict__ ab, const float* __restrict__ alpha,
    const float* __restrict__ bias, const float* __restrict__ Wout,
    const float* __restrict__ bout, float* __restrict__ out, int n) {
  __shared__ float Wl[DHID * NCLS];   // 20 KB
  __shared__ float hl[4][DHID];       // 2 KB
  int t = threadIdx.x;
  for (int i = t; i < DHID * NCLS; i += 256) Wl[i] = Wout[i];
  int wv = t >> 6, lane = t & 63;
  int node = blockIdx.x * 4 + wv;
  if (node < n) {
    int ovfN = *ovf_cnt;
    float al = fminf(fmaxf(alpha[0], 1e-4f), 0.9999f);
    float base = er[node] + ab[0];
    float a[8];
    agg_node8(H, counts, ell, ovf, ovfN, el, ssum, base, al, node, lane, a);
    if (lane < 16) {
      int fl = lane << 3;
#pragma unroll
      for (int i = 0; i < 8; ++i)
        hl[wv][fl + i] = fmaxf(a[i] + bias[fl + i], 0.f);
    }
  }
  __syncthreads();
  if (node >= n) return;
  float z = -INFINITY;
  bool act = lane < NCLS;
  if (act) {
    z = bout[lane];
    const float* hr = hl[wv];
#pragma unroll 8
    for (int k = 0; k < DHID; ++k) z = fmaf(hr[k], Wl[k * NCLS + lane], z);
  }
  float m = z;
#pragma unroll
  for (int off = 32; off; off >>= 1) m = fmaxf(m, __shfl_xor(m, off));
  float p = act ? expf(z - m) : 0.f;
#pragma unroll
  for (int off = 32; off; off >>= 1) p += __shfl_xor(p, off);
  float ls = logf(p);
  if (act) out[(size_t)node * NCLS + lane] = z - m - ls;
}

// ===========================================================================
extern "C" void kernel_launch(void* const* d_in, const int* in_sizes, int n_in,
                              void* d_out, int out_size, void* d_ws, size_t ws_size,
                              hipStream_t stream) {
  const float* x     = (const float*)d_in[0];
  const int*   ei    = (const int*)d_in[1];
  const float* norm  = (const float*)d_in[2];
  const float* W1    = (const float*)d_in[3];
  const float* aW1   = (const float*)d_in[4];
  const float* ab1   = (const float*)d_in[5];
  const float* alpha1= (const float*)d_in[6];
  const float* b1    = (const float*)d_in[7];
  const float* W2    = (const float*)d_in[8];
  const float* aW2   = (const float*)d_in[9];
  const float* ab2   = (const float*)d_in[10];
  const float* alpha2= (const float*)d_in[11];
  const float* b2    = (const float*)d_in[12];
  const float* Wout  = (const float*)d_in[13];
  const float* bout  = (const float*)d_in[14];
  float* out = (float*)d_out;

  const int N  = in_sizes[0] / DHID;
  const int E  = in_sizes[1] / 2;
  const int EP = E + N;

  char* ws = (char*)d_ws;
  size_t off = 0;
  auto alloc = [&](size_t bytes) -> void* {
    void* p = ws + off;
    off += (bytes + 255) & ~(size_t)255;
    return p;
  };
  int*   counts  = (int*)  alloc((size_t)N * 4);
  float* ssum    = (float*)alloc((size_t)N * 4);
  int*   ovf_cnt = (int*)  alloc(256);
  u16*   Wp1     = (u16*)  alloc(16384 * 2);             // packed W1 frags
  u16*   Wp2     = (u16*)  alloc(16384 * 2);             // packed W2 frags
  u16*   Hbf     = (u16*)  alloc((size_t)N * DHID * 2);  // bf16 pre-attn H
  u16*   Bbf     = (u16*)  alloc((size_t)N * DHID * 2);  // bf16 layer-1 out
  float* el      = (float*)alloc((size_t)N * 4);
  float* er      = (float*)alloc((size_t)N * 4);
  uint2* ell     = (uint2*)alloc((size_t)N * ELLW * 8);  // ELL {src, sexp}
  uint4* ovf     = (uint4*)alloc((size_t)EP * 16);       // spill records

  const int gEdge = (EP + 255) / 256;
  const int gT    = (N + 31) / 32;
  const int gAgg  = (N + 3) / 4;
  const int ngrp  = (N + 3) / 4;
  const int gAgg1 = ((ngrp + 3) / 4) * 8;                // (node-group, half)
  const int prepWork = N + 32768 + 1;
  const int gPrep = (prepWork + 255) / 256;

  // K0: prep (zero + W packs)
  prep_kernel<<<gPrep, 256, 0, stream>>>(W1, W2, Wp1, Wp2,
                                         counts, ssum, ovf_cnt, N);
  // K2: mfma gemm1 (fp32 x, in-register bf16 pack) || one-pass ELL build
  gemm1_build_kernel<<<gT + gEdge, 256, 0, stream>>>(
      x, Wp1, aW1, Hbf, el, er, N, gT, ei, norm, counts, ssum, ell, ovf,
      ovf_cnt, E, EP);
  // K3: agg layer 1 -> Bbf (feature-split, XCD-affine halves)
  agg1_split_kernel<<<gAgg1, 256, 0, stream>>>(Hbf, counts, ell, ovf, ovf_cnt,
                                               el, er, ssum, ab1, alpha1, b1,
                                               Bbf, N, ngrp);
  // K4: mfma gemm2 (bf16 in)
  gemm_elr_kernel<<<gT, 256, 0, stream>>>(Bbf, Wp2, aW2, Hbf, el, er, N);
  // K5: agg layer 2 + head
  agg_head_kernel<<<gAgg, 256, 0, stream>>>(Hbf, counts, ell, ovf, ovf_cnt,
                                            el, er, ssum, ab2, alpha2, b2,
                                            Wout, bout, out, N);
}

// Round 15
// 104.716 us; speedup vs baseline: 1.0686x; 1.0686x over previous
//
#include <hip/hip_runtime.h>
#include <math.h>

#define DHID 128
#define NCLS 40
#define ELLW 64

typedef unsigned int   u32;
typedef unsigned short u16;
using short8 = __attribute__((ext_vector_type(8))) short;
using f32x4  = __attribute__((ext_vector_type(4))) float;

// round-to-nearest-even f32 -> bf16
__device__ __forceinline__ u16 f2bf(float f) {
  u32 u = __float_as_uint(f);
  return (u16)((u + 0x7FFFu + ((u >> 16) & 1u)) >> 16);
}
__device__ __forceinline__ float bf_lo(u32 p) { return __uint_as_float(p << 16); }
__device__ __forceinline__ float bf_hi(u32 p) { return __uint_as_float(p & 0xFFFF0000u); }

// ============ K0: prep = zero + cvt x->bf16 + pack W1/W2 frags ==============
// Wp layout: frag block (ct,kt): 64 lanes x 8 bf16; elem (l,j) =
//   W[kt*32 + (l>>4)*8 + j][ct*16 + (l&15)]  (B-operand of 16x16x32 bf16)
__global__ __launch_bounds__(256) void prep_kernel(
    const float* __restrict__ x, const float* __restrict__ W1,
    const float* __restrict__ W2, u16* __restrict__ xbf,
    u16* __restrict__ Wp1, u16* __restrict__ Wp2,
    int* __restrict__ counts, float* __restrict__ ssum,
    int* __restrict__ ovf_cnt, int N) {
  int gi = blockIdx.x * 256 + threadIdx.x;
  int Ncvt = N * 16;                       // N*128/8 threads, 8 elems each
  if (gi < Ncvt) {
    int base = gi * 8;
    float4 v0 = *reinterpret_cast<const float4*>(x + base);
    float4 v1 = *reinterpret_cast<const float4*>(x + base + 4);
    uint4 o;
    o.x = (u32)f2bf(v0.x) | ((u32)f2bf(v0.y) << 16);
    o.y = (u32)f2bf(v0.z) | ((u32)f2bf(v0.w) << 16);
    o.z = (u32)f2bf(v1.x) | ((u32)f2bf(v1.y) << 16);
    o.w = (u32)f2bf(v1.z) | ((u32)f2bf(v1.w) << 16);
    *reinterpret_cast<uint4*>(xbf + base) = o;
    return;
  }
  gi -= Ncvt;
  if (gi < N) { counts[gi] = 0; ssum[gi] = 0.f; return; }
  gi -= N;
  if (gi < 32768) {                        // 2 layers x 16384
    int layer = gi >> 14, q = gi & 16383;
    int j = q & 7, l = (q >> 3) & 63, kt = (q >> 9) & 3, ct = q >> 11;
    int k = kt * 32 + (l >> 4) * 8 + j;
    int col = ct * 16 + (l & 15);
    const float* Wsrc = layer ? W2 : W1;
    u16* Wdst = layer ? Wp2 : Wp1;
    Wdst[q] = f2bf(Wsrc[k * DHID + col]);
    return;
  }
  gi -= 32768;
  if (gi == 0) *ovf_cnt = 0;
}

// ============ MFMA GEMM block: H[rowBase..+32] = bf16(Xbf @ W), el, er ======
__device__ __forceinline__ void mfma_gemm_block(
    float* Cl, float* P, const u16* __restrict__ Xbf,
    const u16* __restrict__ Wp, const float* __restrict__ aW,
    u16* __restrict__ Hout, float* __restrict__ elo, float* __restrict__ ero,
    int n, int rowBase) {
  int t = threadIdx.x;
  int w = t >> 6, l = t & 63;
  int lr = l & 15, lh = l >> 4;
  f32x4 acc00 = {0.f,0.f,0.f,0.f}, acc01 = {0.f,0.f,0.f,0.f};
  f32x4 acc10 = {0.f,0.f,0.f,0.f}, acc11 = {0.f,0.f,0.f,0.f};
  int r0 = rowBase + lr;      if (r0 > n - 1) r0 = n - 1;
  int r1 = rowBase + 16 + lr; if (r1 > n - 1) r1 = n - 1;
  const u16* a0p = Xbf + (size_t)r0 * DHID;
  const u16* a1p = Xbf + (size_t)r1 * DHID;
  const u16* wb0 = Wp + ((size_t)(w * 2 + 0) * 4 * 64 + l) * 8;
  const u16* wb1 = Wp + ((size_t)(w * 2 + 1) * 4 * 64 + l) * 8;
#pragma unroll
  for (int kt = 0; kt < 4; ++kt) {
    int ko = kt * 32 + lh * 8;
    short8 fa0 = *reinterpret_cast<const short8*>(a0p + ko);
    short8 fa1 = *reinterpret_cast<const short8*>(a1p + ko);
    short8 fb0 = *reinterpret_cast<const short8*>(wb0 + kt * 64 * 8);
    short8 fb1 = *reinterpret_cast<const short8*>(wb1 + kt * 64 * 8);
    acc00 = __builtin_amdgcn_mfma_f32_16x16x32_bf16(fa0, fb0, acc00, 0, 0, 0);
    acc01 = __builtin_amdgcn_mfma_f32_16x16x32_bf16(fa0, fb1, acc01, 0, 0, 0);
    acc10 = __builtin_amdgcn_mfma_f32_16x16x32_bf16(fa1, fb0, acc10, 0, 0, 0);
    acc11 = __builtin_amdgcn_mfma_f32_16x16x32_bf16(fa1, fb1, acc11, 0, 0, 0);
  }
  // C->LDS: row = rt*16 + lh*4 + j, col = w*32 + c*16 + lr
#pragma unroll
  for (int j = 0; j < 4; ++j) {
    Cl[(lh * 4 + j) * DHID + w * 32 + lr]           = acc00[j];
    Cl[(lh * 4 + j) * DHID + w * 32 + 16 + lr]      = acc01[j];
    Cl[(16 + lh * 4 + j) * DHID + w * 32 + lr]      = acc10[j];
    Cl[(16 + lh * 4 + j) * DHID + w * 32 + 16 + lr] = acc11[j];
  }
  __syncthreads();
  // thread t: row r=t>>3, cols (t&7)*16..+15 : bf16 H write + elr partials
  int r = t >> 3, cg2 = (t & 7) * 16;
  const float* crow = Cl + r * DHID + cg2;
  float pl = 0.f, pr = 0.f;
  int gr = rowBase + r;
#pragma unroll
  for (int q = 0; q < 16; ++q) {
    float v = crow[q];
    pl = fmaf(v, aW[cg2 + q], pl);
    pr = fmaf(v, aW[DHID + cg2 + q], pr);
  }
  if (gr < n) {
    uint4 o;
    o.x = (u32)f2bf(crow[0])  | ((u32)f2bf(crow[1])  << 16);
    o.y = (u32)f2bf(crow[2])  | ((u32)f2bf(crow[3])  << 16);
    o.z = (u32)f2bf(crow[4])  | ((u32)f2bf(crow[5])  << 16);
    o.w = (u32)f2bf(crow[6])  | ((u32)f2bf(crow[7])  << 16);
    *reinterpret_cast<uint4*>(Hout + (size_t)gr * DHID + cg2) = o;
    uint4 o2;
    o2.x = (u32)f2bf(crow[8])  | ((u32)f2bf(crow[9])  << 16);
    o2.y = (u32)f2bf(crow[10]) | ((u32)f2bf(crow[11]) << 16);
    o2.z = (u32)f2bf(crow[12]) | ((u32)f2bf(crow[13]) << 16);
    o2.w = (u32)f2bf(crow[14]) | ((u32)f2bf(crow[15]) << 16);
    *reinterpret_cast<uint4*>(Hout + (size_t)gr * DHID + cg2 + 8) = o2;
  }
  P[r * 16 + (t & 7) * 2 + 0] = pl;
  P[r * 16 + (t & 7) * 2 + 1] = pr;
  __syncthreads();
  if (t < 64) {
    int half = t >> 5, rr = t & 31;
    float s = 0.f;
#pragma unroll
    for (int cq = 0; cq < 8; ++cq) s += P[rr * 16 + cq * 2 + half];
    int g2 = rowBase + rr;
    if (g2 < n) { if (half) ero[g2] = s; else elo[g2] = s; }
  }
}

// ============ K2: mfma gemm1 (blocks < gT) || ELL build (blocks >= gT) ======
__global__ __launch_bounds__(256) void gemm1_build_kernel(
    const u16* __restrict__ Xbf, const u16* __restrict__ Wp,
    const float* __restrict__ aW, u16* __restrict__ H,
    float* __restrict__ el, float* __restrict__ er, int n, int gT,
    const int* __restrict__ ei, const float* __restrict__ norm,
    int* __restrict__ counts, float* __restrict__ ssum,
    uint2* __restrict__ ell, uint4* __restrict__ ovf,
    int* __restrict__ ovf_cnt, int E, int EP) {
  __shared__ float Cl[32 * DHID];   // 16 KB
  __shared__ float P[32 * 16];      // 2 KB
  if (blockIdx.x < gT) {
    mfma_gemm_block(Cl, P, Xbf, Wp, aW, H, el, er, n, blockIdx.x * 32);
  } else {
    int k = (blockIdx.x - gT) * 256 + threadIdx.x;
    if (k < EP) {
      int src, dst;
      if (k < E) { src = ei[k]; dst = ei[E + k]; }
      else       { src = dst = k - E; }
      float se = __expf(norm[k]);
      atomicAdd(&ssum[src], se);
      int slot = atomicAdd(&counts[dst], 1);
      if (slot < ELLW) {
        ell[(size_t)dst * ELLW + slot] =
            make_uint2((u32)src, __float_as_uint(se));
      } else {
        int o = atomicAdd(ovf_cnt, 1);
        ovf[o] = make_uint4((u32)dst, (u32)src, __float_as_uint(se), 0u);
      }
    }
  }
}

// ============ K4: standalone mfma gemm2 =====================================
__global__ __launch_bounds__(256) void gemm_elr_kernel(
    const u16* __restrict__ Xbf, const u16* __restrict__ Wp,
    const float* __restrict__ aW, u16* __restrict__ H,
    float* __restrict__ el, float* __restrict__ er, int n) {
  __shared__ float Cl[32 * DHID];
  __shared__ float P[32 * 16];
  mfma_gemm_block(Cl, P, Xbf, Wp, aW, H, el, er, n, blockIdx.x * 32);
}

// ============ per-node max-aggregation over bf16 H (one wave, ELL) ==========
// Lane j owns ELL edge j. The FIRST 12 edges' H-rows are prefetched (3 uint4
// in flight; addresses depend only on src) BEFORE the softmax exp/reduce
// chain, hiding gather latency under it. Remainder streamed quarter-wave.
__device__ __forceinline__ void agg_node8(
    const u16* __restrict__ H, const int* __restrict__ counts,
    const uint2* __restrict__ ell, const uint4* __restrict__ ovf, int ovfN,
    const float* __restrict__ el, const float* __restrict__ ssum,
    float base, float al, int node, int lane, float a[8]) {
  int deg = counts[node];
  int dell = deg < ELLW ? deg : ELLW;
  const uint2* erow = ell + (size_t)node * ELLW;
  int src0 = 0; float sx0 = 0.f;
  if (lane < dell) {
    uint2 rec = erow[lane];
    src0 = (int)rec.x;
    sx0  = __uint_as_float(rec.y);
  }
  // ---- prefetch first 12 edges' rows (overlaps softmax below) ----
  int qw = lane >> 4;
  const u16* Hf = H + ((lane & 15) << 3);          // this lane's 8 features
  int ei0 = qw, ei1 = 4 + qw, ei2 = 8 + qw;
  int ci0 = ei0 < dell ? ei0 : 0;                  // deg >= 1 (self-loop)
  int ci1 = ei1 < dell ? ei1 : 0;
  int ci2 = ei2 < dell ? ei2 : 0;
  int ps0 = __shfl(src0, ci0);
  int ps1 = __shfl(src0, ci1);
  int ps2 = __shfl(src0, ci2);
  uint4 pr0 = *reinterpret_cast<const uint4*>(Hf + (size_t)ps0 * DHID);
  uint4 pr1 = *reinterpret_cast<const uint4*>(Hf + (size_t)ps1 * DHID);
  uint4 pr2 = *reinterpret_cast<const uint4*>(Hf + (size_t)ps2 * DHID);
  // ---- softmax denominator ----
  float e0 = 0.f;
  if (lane < dell) {
    float g = el[src0] + base;
    e0 = __expf(g > 0.f ? g : 0.2f * g);
  }
  float es = e0;
  if (ovfN > 0 && deg > ELLW) {                    // rare spill
    for (int cb = 0; cb < ovfN; cb += 64) {
      int i = cb + lane;
      if (i < ovfN) {
        uint4 r = ovf[i];
        if ((int)r.x == node) {
          float g = el[(int)r.y] + base;
          es += __expf(g > 0.f ? g : 0.2f * g);
        }
      }
    }
  }
#pragma unroll
  for (int off = 32; off; off >>= 1) es += __shfl_xor(es, off);
  float invEs = al / es;
  float omaS  = (1.f - al) / ssum[node];
  float w0 = e0 * invEs + sx0 * omaS;
#pragma unroll
  for (int i = 0; i < 8; ++i) a[i] = -INFINITY;
  // ---- consume prefetched rows ----
  {
    float wA = __shfl(w0, ci0);
    float wB = __shfl(w0, ci1);
    float wC = __shfl(w0, ci2);
    if (ei0 < dell) {
      a[0] = fmaxf(a[0], wA * bf_lo(pr0.x)); a[1] = fmaxf(a[1], wA * bf_hi(pr0.x));
      a[2] = fmaxf(a[2], wA * bf_lo(pr0.y)); a[3] = fmaxf(a[3], wA * bf_hi(pr0.y));
      a[4] = fmaxf(a[4], wA * bf_lo(pr0.z)); a[5] = fmaxf(a[5], wA * bf_hi(pr0.z));
      a[6] = fmaxf(a[6], wA * bf_lo(pr0.w)); a[7] = fmaxf(a[7], wA * bf_hi(pr0.w));
    }
    if (ei1 < dell) {
      a[0] = fmaxf(a[0], wB * bf_lo(pr1.x)); a[1] = fmaxf(a[1], wB * bf_hi(pr1.x));
      a[2] = fmaxf(a[2], wB * bf_lo(pr1.y)); a[3] = fmaxf(a[3], wB * bf_hi(pr1.y));
      a[4] = fmaxf(a[4], wB * bf_lo(pr1.z)); a[5] = fmaxf(a[5], wB * bf_hi(pr1.z));
      a[6] = fmaxf(a[6], wB * bf_lo(pr1.w)); a[7] = fmaxf(a[7], wB * bf_hi(pr1.w));
    }
    if (ei2 < dell) {
      a[0] = fmaxf(a[0], wC * bf_lo(pr2.x)); a[1] = fmaxf(a[1], wC * bf_hi(pr2.x));
      a[2] = fmaxf(a[2], wC * bf_lo(pr2.y)); a[3] = fmaxf(a[3], wC * bf_hi(pr2.y));
      a[4] = fmaxf(a[4], wC * bf_lo(pr2.z)); a[5] = fmaxf(a[5], wC * bf_hi(pr2.z));
      a[6] = fmaxf(a[6], wC * bf_lo(pr2.w)); a[7] = fmaxf(a[7], wC * bf_hi(pr2.w));
    }
  }
  // ---- stream remaining edges (12..dell) ----
  int j = 12;
  for (; j + 7 < dell; j += 8) {
    int ea = j + qw, eb = j + 4 + qw;
    int   sa = __shfl(src0, ea); float wa = __shfl(w0, ea);
    int   sb = __shfl(src0, eb); float wb = __shfl(w0, eb);
    uint4 ha = *reinterpret_cast<const uint4*>(Hf + (size_t)sa * DHID);
    uint4 hb = *reinterpret_cast<const uint4*>(Hf + (size_t)sb * DHID);
    a[0] = fmaxf(a[0], fmaxf(wa * bf_lo(ha.x), wb * bf_lo(hb.x)));
    a[1] = fmaxf(a[1], fmaxf(wa * bf_hi(ha.x), wb * bf_hi(hb.x)));
    a[2] = fmaxf(a[2], fmaxf(wa * bf_lo(ha.y), wb * bf_lo(hb.y)));
    a[3] = fmaxf(a[3], fmaxf(wa * bf_hi(ha.y), wb * bf_hi(hb.y)));
    a[4] = fmaxf(a[4], fmaxf(wa * bf_lo(ha.z), wb * bf_lo(hb.z)));
    a[5] = fmaxf(a[5], fmaxf(wa * bf_hi(ha.z), wb * bf_hi(hb.z)));
    a[6] = fmaxf(a[6], fmaxf(wa * bf_lo(ha.w), wb * bf_lo(hb.w)));
    a[7] = fmaxf(a[7], fmaxf(wa * bf_hi(ha.w), wb * bf_hi(hb.w)));
  }
  for (; j < dell; j += 4) {                       // tail
    int e = j + qw;
    int ec = e < dell ? e : dell - 1;
    int   sa = __shfl(src0, ec); float wa = __shfl(w0, ec);
    if (e < dell) {
      uint4 ha = *reinterpret_cast<const uint4*>(Hf + (size_t)sa * DHID);
      a[0] = fmaxf(a[0], wa * bf_lo(ha.x));
      a[1] = fmaxf(a[1], wa * bf_hi(ha.x));
      a[2] = fmaxf(a[2], wa * bf_lo(ha.y));
      a[3] = fmaxf(a[3], wa * bf_hi(ha.y));
      a[4] = fmaxf(a[4], wa * bf_lo(ha.z));
      a[5] = fmaxf(a[5], wa * bf_hi(ha.z));
      a[6] = fmaxf(a[6], wa * bf_lo(ha.w));
      a[7] = fmaxf(a[7], wa * bf_hi(ha.w));
    }
  }
  // ---- overflow gather (rare) ----
  if (ovfN > 0 && deg > ELLW) {
    for (int cb = 0; cb < ovfN; cb += 64) {
      int i = cb + lane;
      uint4 r = (i < ovfN) ? ovf[i] : make_uint4(0u, 0u, 0u, 0u);
      bool match = (i < ovfN) && ((int)r.x == node);
      int si = (int)r.y;
      float wi = 0.f;
      if (match) {
        float g = el[si] + base;
        wi = __expf(g > 0.f ? g : 0.2f * g) * invEs +
             __uint_as_float(r.z) * omaS;
      }
      unsigned long long mask = __ballot(match);
      while (mask) {
        int jb = __ffsll(mask) - 1;
        mask &= mask - 1;
        int   sj = __shfl(si, jb);
        float wj = __shfl(wi, jb);
        uint4 h = *reinterpret_cast<const uint4*>(Hf + (size_t)sj * DHID);
        a[0] = fmaxf(a[0], wj * bf_lo(h.x)); a[1] = fmaxf(a[1], wj * bf_hi(h.x));
        a[2] = fmaxf(a[2], wj * bf_lo(h.y)); a[3] = fmaxf(a[3], wj * bf_hi(h.y));
        a[4] = fmaxf(a[4], wj * bf_lo(h.z)); a[5] = fmaxf(a[5], wj * bf_hi(h.z));
        a[6] = fmaxf(a[6], wj * bf_lo(h.w)); a[7] = fmaxf(a[7], wj * bf_hi(h.w));
      }
    }
  }
#pragma unroll
  for (int i = 0; i < 8; ++i) {
    a[i] = fmaxf(a[i], __shfl_xor(a[i], 16));
    a[i] = fmaxf(a[i], __shfl_xor(a[i], 32));
  }
}

// ============ K3: agg1 -> B (bf16) ==========================================
__global__ __launch_bounds__(256) void agg_kernel(
    const u16* __restrict__ H, const int* __restrict__ counts,
    const uint2* __restrict__ ell, const uint4* __restrict__ ovf,
    const int* __restrict__ ovf_cnt, const float* __restrict__ el,
    const float* __restrict__ er, const float* __restrict__ ssum,
    const float* __restrict__ ab, const float* __restrict__ alpha,
    const float* __restrict__ bias, u16* __restrict__ Y, int n) {
  int node = blockIdx.x * 4 + (threadIdx.x >> 6);
  int lane = threadIdx.x & 63;
  if (node >= n) return;
  int ovfN = *ovf_cnt;
  float al = fminf(fmaxf(alpha[0], 1e-4f), 0.9999f);
  float base = er[node] + ab[0];
  float a[8];
  agg_node8(H, counts, ell, ovf, ovfN, el, ssum, base, al, node, lane, a);
  if (lane < 16) {
    int fl = lane << 3;
    float v[8];
#pragma unroll
    for (int i = 0; i < 8; ++i) v[i] = fmaxf(a[i] + bias[fl + i], 0.f);
    uint4 o;
    o.x = (u32)f2bf(v[0]) | ((u32)f2bf(v[1]) << 16);
    o.y = (u32)f2bf(v[2]) | ((u32)f2bf(v[3]) << 16);
    o.z = (u32)f2bf(v[4]) | ((u32)f2bf(v[5]) << 16);
    o.w = (u32)f2bf(v[6]) | ((u32)f2bf(v[7]) << 16);
    *reinterpret_cast<uint4*>(Y + (size_t)node * DHID + fl) = o;
  }
}

// ============ K5: agg2 + head ===============================================
__global__ __launch_bounds__(256) void agg_head_kernel(
    const u16* __restrict__ H, const int* __restrict__ counts,
    const uint2* __restrict__ ell, const uint4* __restrict__ ovf,
    const int* __restrict__ ovf_cnt, const float* __restrict__ el,
    const float* __restrict__ er, const float* __restrict__ ssum,
    const float* __restrict__ ab, const float* __restrict__ alpha,
    const float* __restrict__ bias, const float* __restrict__ Wout,
    const float* __restrict__ bout, float* __restrict__ out, int n) {
  __shared__ float Wl[DHID * NCLS];   // 20 KB
  __shared__ float hl[4][DHID];       // 2 KB
  int t = threadIdx.x;
  for (int i = t; i < DHID * NCLS; i += 256) Wl[i] = Wout[i];
  int wv = t >> 6, lane = t & 63;
  int node = blockIdx.x * 4 + wv;
  if (node < n) {                      // wave-uniform branch
    int ovfN = *ovf_cnt;
    float al = fminf(fmaxf(alpha[0], 1e-4f), 0.9999f);
    float base = er[node] + ab[0];
    float a[8];
    agg_node8(H, counts, ell, ovf, ovfN, el, ssum, base, al, node, lane, a);
    if (lane < 16) {
      int fl = lane << 3;
#pragma unroll
      for (int i = 0; i < 8; ++i)
        hl[wv][fl + i] = fmaxf(a[i] + bias[fl + i], 0.f);
    }
  }
  __syncthreads();
  if (node >= n) return;
  float z = -INFINITY;
  bool act = lane < NCLS;
  if (act) {
    z = bout[lane];
    const float* hr = hl[wv];
#pragma unroll 8
    for (int k = 0; k < DHID; ++k) z = fmaf(hr[k], Wl[k * NCLS + lane], z);
  }
  float m = z;
#pragma unroll
  for (int off = 32; off; off >>= 1) m = fmaxf(m, __shfl_xor(m, off));
  float p = act ? expf(z - m) : 0.f;
#pragma unroll
  for (int off = 32; off; off >>= 1) p += __shfl_xor(p, off);
  float ls = logf(p);
  if (act) out[(size_t)node * NCLS + lane] = z - m - ls;
}

// ===========================================================================
extern "C" void kernel_launch(void* const* d_in, const int* in_sizes, int n_in,
                              void* d_out, int out_size, void* d_ws, size_t ws_size,
                              hipStream_t stream) {
  const float* x     = (const float*)d_in[0];
  const int*   ei    = (const int*)d_in[1];
  const float* norm  = (const float*)d_in[2];
  const float* W1    = (const float*)d_in[3];
  const float* aW1   = (const float*)d_in[4];
  const float* ab1   = (const float*)d_in[5];
  const float* alpha1= (const float*)d_in[6];
  const float* b1    = (const float*)d_in[7];
  const float* W2    = (const float*)d_in[8];
  const float* aW2   = (const float*)d_in[9];
  const float* ab2   = (const float*)d_in[10];
  const float* alpha2= (const float*)d_in[11];
  const float* b2    = (const float*)d_in[12];
  const float* Wout  = (const float*)d_in[13];
  const float* bout  = (const float*)d_in[14];
  float* out = (float*)d_out;

  const int N  = in_sizes[0] / DHID;
  const int E  = in_sizes[1] / 2;
  const int EP = E + N;

  char* ws = (char*)d_ws;
  size_t off = 0;
  auto alloc = [&](size_t bytes) -> void* {
    void* p = ws + off;
    off += (bytes + 255) & ~(size_t)255;
    return p;
  };
  int*   counts  = (int*)  alloc((size_t)N * 4);
  float* ssum    = (float*)alloc((size_t)N * 4);
  int*   ovf_cnt = (int*)  alloc(256);
  u16*   xbf     = (u16*)  alloc((size_t)N * DHID * 2);  // bf16 input x
  u16*   Wp1     = (u16*)  alloc(16384 * 2);             // packed W1 frags
  u16*   Wp2     = (u16*)  alloc(16384 * 2);             // packed W2 frags
  u16*   Hbf     = (u16*)  alloc((size_t)N * DHID * 2);  // bf16 pre-attn H
  u16*   Bbf     = (u16*)  alloc((size_t)N * DHID * 2);  // bf16 layer-1 out
  float* el      = (float*)alloc((size_t)N * 4);
  float* er      = (float*)alloc((size_t)N * 4);
  uint2* ell     = (uint2*)alloc((size_t)N * ELLW * 8);  // ELL {src, sexp}
  uint4* ovf     = (uint4*)alloc((size_t)EP * 16);       // spill records

  const int gEdge = (EP + 255) / 256;
  const int gT    = (N + 31) / 32;
  const int gAgg  = (N + 3) / 4;
  const int prepWork = N * 16 + N + 32768 + 1;
  const int gPrep = (prepWork + 255) / 256;

  // K0: prep (zero + x->bf16 + W packs)
  prep_kernel<<<gPrep, 256, 0, stream>>>(x, W1, W2, xbf, Wp1, Wp2,
                                         counts, ssum, ovf_cnt, N);
  // K2: mfma gemm1 || one-pass ELL build
  gemm1_build_kernel<<<gT + gEdge, 256, 0, stream>>>(
      xbf, Wp1, aW1, Hbf, el, er, N, gT, ei, norm, counts, ssum, ell, ovf,
      ovf_cnt, E, EP);
  // K3: agg layer 1 -> Bbf (bf16)
  agg_kernel<<<gAgg, 256, 0, stream>>>(Hbf, counts, ell, ovf, ovf_cnt, el, er,
                                       ssum, ab1, alpha1, b1, Bbf, N);
  // K4: mfma gemm2
  gemm_elr_kernel<<<gT, 256, 0, stream>>>(Bbf, Wp2, aW2, Hbf, el, er, N);
  // K5: agg layer 2 + head
  agg_head_kernel<<<gAgg, 256, 0, stream>>>(Hbf, counts, ell, ovf, ovf_cnt,
                                            el, er, ssum, ab2, alpha2, b2,
                                            Wout, bout, out, N);
}